// Round 5
// baseline (344.099 us; speedup 1.0000x reference)
//
#include <hip/hip_runtime.h>

#define HID 128
#define LN_EPS 1e-5f

using f32x4 = __attribute__((ext_vector_type(4))) float;
using s16x8 = __attribute__((ext_vector_type(8))) short;

__device__ inline float bl2f(unsigned u) { u <<= 16; return __builtin_bit_cast(float, u); }
__device__ inline float bh2f(unsigned u) { u &= 0xffff0000u; return __builtin_bit_cast(float, u); }
__device__ inline unsigned f2b_bits(float f) {
  unsigned u = __builtin_bit_cast(unsigned, f);
  return (u + 0x7fffu + ((u >> 16) & 1u)) >> 16;  // RNE
}
__device__ inline short f2b(float f) { return (short)f2b_bits(f); }
__device__ inline unsigned pack2(float a, float b) { return f2b_bits(a) | (f2b_bits(b) << 16); }

__device__ inline void addu4(const uint4 u, float a[8]) {
  a[0] += bl2f(u.x); a[1] += bh2f(u.x);
  a[2] += bl2f(u.y); a[3] += bh2f(u.y);
  a[4] += bl2f(u.z); a[5] += bh2f(u.z);
  a[6] += bl2f(u.w); a[7] += bh2f(u.w);
}

// ---------------- combined pre-weight: Wc = W_pre @ convW0 (fp32), b' = b_pre @ convW0 ----------------

__global__ __launch_bounds__(128) void prep_comb_kernel(const float* __restrict__ W_pre,
                                                        const float* __restrict__ b_pre,
                                                        const float* __restrict__ convW0,
                                                        float* __restrict__ Wc,
                                                        float* __restrict__ bprime) {
  int m = blockIdx.x;  // 0..127 rows of W_pre; 128 -> bias row
  int t = threadIdx.x;
  const float* arow = (m == HID) ? b_pre : W_pre + (size_t)m * HID;
  float acc = 0.f;
  #pragma unroll 8
  for (int k = 0; k < HID; ++k) acc = fmaf(arow[k], convW0[(size_t)k * HID + t], acc);
  if (m == HID) bprime[t] = acc;
  else Wc[(size_t)m * HID + t] = acc;
}

// ---------------- weight prep: Wt[w][n][k] = bf16(src_w[k][n]) ----------------

__global__ __launch_bounds__(64) void prep_w_kernel(const float* __restrict__ Wc,
                                                    const float* __restrict__ conv_W,
                                                    short* __restrict__ Wt) {
  int b = blockIdx.x;            // 0..511
  int w = b >> 7, n = b & 127;
  const float* W = (w == 0) ? Wc : conv_W + (size_t)w * HID * HID;
  int t = threadIdx.x;           // k = 2t, 2t+1
  float f0 = W[(2 * t) * HID + n];
  float f1 = W[(2 * t + 1) * HID + n];
  ((unsigned*)Wt)[(size_t)(w * HID + n) * 64 + t] = pack2(f0, f1);
}

// ---------------- CSR build (scan-free) ----------------

__global__ void zero_ints_kernel(int* __restrict__ p, int n) {
  int i = blockIdx.x * blockDim.x + threadIdx.x;
  if (i < n) p[i] = 0;
}

__global__ void deg_count_kernel(const int* __restrict__ dst, int E, int* __restrict__ deg) {
  int e = blockIdx.x * blockDim.x + threadIdx.x;
  if (e < E) atomicAdd(&deg[dst[e]], 1);
}

__global__ __launch_bounds__(256) void alloc_kernel(const int* __restrict__ deg,
                                                    int* __restrict__ start,
                                                    int* __restrict__ cur,
                                                    float* __restrict__ dinv,
                                                    int* __restrict__ cnt, int n) {
  __shared__ int wt[4];
  __shared__ int bbase;
  int t = threadIdx.x, lane = t & 63, wid = t >> 6;
  int i = blockIdx.x * 256 + t;
  int d = (i < n) ? deg[i] : 0;
  int x = d;
  #pragma unroll
  for (int off = 1; off < 64; off <<= 1) {
    int u = __shfl_up(x, off, 64);
    if (lane >= off) x += u;
  }
  if (lane == 63) wt[wid] = x;
  __syncthreads();
  if (t == 0) bbase = atomicAdd(cnt, wt[0] + wt[1] + wt[2] + wt[3]);
  __syncthreads();
  int wbase = bbase;
  for (int w = 0; w < wid; ++w) wbase += wt[w];
  int excl = wbase + x - d;
  if (i < n) {
    start[i] = excl;
    cur[i] = excl;
    dinv[i] = rsqrtf((float)(d + 1));
  }
}

__global__ void fill_csr_kernel(const int* __restrict__ src, const int* __restrict__ dst,
                                int E, int* __restrict__ cur, int* __restrict__ col) {
  int e = blockIdx.x * blockDim.x + threadIdx.x;
  if (e < E) {
    int d = dst[e];
    int p = atomicAdd(&cur[d], 1);
    col[p] = src[e];
  }
}

// ---------------- MFMA GEMM (cell-0 only): Y = X(f32)@Wt^T, epi (acc+bias)*dinv ----------------

template<bool AF32>
__global__ __launch_bounds__(256) void gemm_mfma_kernel(
    const void* __restrict__ Xv, const short* __restrict__ Wt,
    const float* __restrict__ bias, const float* __restrict__ dinv,
    short* __restrict__ Y, int M) {
  __shared__ short lds[4 * 32 * HID];  // 32 KB
  int t = threadIdx.x;
  int wave = t >> 6, l = t & 63;
  int lg = l >> 4, lr = l & 15;
  int mb = blockIdx.x * 128 + wave * 32;

  const f32x4 z4 = {0.f, 0.f, 0.f, 0.f};
  f32x4 acc[2][8];
  #pragma unroll
  for (int i = 0; i < 2; ++i)
    #pragma unroll
    for (int j = 0; j < 8; ++j) acc[i][j] = z4;

  const short* Xb = (const short*)Xv;
  const float* Xf = (const float*)Xv;

  #pragma unroll
  for (int kk = 0; kk < 4; ++kk) {
    int k0 = kk * 32 + lg * 8;
    s16x8 a[2];
    #pragma unroll
    for (int mf = 0; mf < 2; ++mf) {
      int row = mb + mf * 16 + lr;
      s16x8 av = {0, 0, 0, 0, 0, 0, 0, 0};
      if (row < M) {
        if constexpr (AF32) {
          const float4* p = (const float4*)(Xf + (size_t)row * HID + k0);
          float4 x0 = p[0], x1 = p[1];
          av[0] = f2b(x0.x); av[1] = f2b(x0.y); av[2] = f2b(x0.z); av[3] = f2b(x0.w);
          av[4] = f2b(x1.x); av[5] = f2b(x1.y); av[6] = f2b(x1.z); av[7] = f2b(x1.w);
        } else {
          av = *(const s16x8*)(Xb + (size_t)row * HID + k0);
        }
      }
      a[mf] = av;
    }
    #pragma unroll
    for (int nf = 0; nf < 8; ++nf) {
      s16x8 b = *(const s16x8*)(Wt + (size_t)(nf * 16 + lr) * HID + k0);
      acc[0][nf] = __builtin_amdgcn_mfma_f32_16x16x32_bf16(a[0], b, acc[0][nf], 0, 0, 0);
      acc[1][nf] = __builtin_amdgcn_mfma_f32_16x16x32_bf16(a[1], b, acc[1][nf], 0, 0, 0);
    }
  }

  float bv[8];
  #pragma unroll
  for (int nf = 0; nf < 8; ++nf) bv[nf] = bias ? bias[nf * 16 + lr] : 0.f;

  short* wsl = lds + wave * 32 * HID;
  #pragma unroll
  for (int mf = 0; mf < 2; ++mf) {
    #pragma unroll
    for (int r = 0; r < 4; ++r) {
      int ri = mf * 16 + lg * 4 + r;
      int row = mb + ri;
      float dv = 1.f;
      if (dinv && row < M) dv = dinv[row];
      #pragma unroll
      for (int nf = 0; nf < 8; ++nf) {
        float v = (acc[mf][nf][r] + bv[nf]) * dv;
        wsl[ri * HID + nf * 16 + lr] = f2b(v);
      }
    }
  }
  __syncthreads();

  #pragma unroll
  for (int it = 0; it < 8; ++it) {
    int ro = it * 4 + lg;
    int row = mb + ro;
    s16x8 v = *(const s16x8*)(wsl + it * 512 + l * 8);
    if (row < M) *(s16x8*)(Y + (size_t)row * HID + lr * 8) = v;
  }
}

// ---------------- FUSED: aggregate + LN + ReLU + next-cell GEMM ----------------
// 64 nodes/block, 4 waves, 16 nodes/wave. Phase 1: per node, gather G_in rows
// (16B/lane, 4 sub-groups = 4 rows per VMEM instr), LN in registers, update ACC,
// write bf16 row to swizzled LDS A-tile. Phase 2: per-wave 16x128 MFMA GEMM
// (A from own LDS rows, B=Wt from global), epilogue *dinv -> G_out.
// No __syncthreads needed: each wave only touches its own 16 LDS rows.
// mode 0: gemm-in = y, ACC = y;  mode 1: gemm-in = ACC+y, ACC = ACC+y.

__global__ __launch_bounds__(256) void agg_ln_gemm_kernel(
    const short* __restrict__ G_in, const int* __restrict__ start,
    const int* __restrict__ deg, const float* __restrict__ dinv,
    const float* __restrict__ bias, const float* __restrict__ lng,
    const float* __restrict__ lnb, const int* __restrict__ col,
    short* __restrict__ ACC, const short* __restrict__ Wt,
    short* __restrict__ G_out, int N, int mode) {
  __shared__ short As[64 * HID];  // 16 KB
  int t = threadIdx.x;
  int wave = t >> 6, l = t & 63, lr = l & 15, sub = l >> 4;
  const uint4* GR = (const uint4*)G_in;
  uint4* Aw = (uint4*)ACC;

  // hoisted per-cell constants (wave-uniform in lr)
  const float4* bp4 = (const float4*)(bias + 8 * lr);
  const float4* gp4 = (const float4*)(lng + 8 * lr);
  const float4* pp4 = (const float4*)(lnb + 8 * lr);
  float4 bc0 = bp4[0], bc1 = bp4[1];
  float4 g0 = gp4[0], g1 = gp4[1];
  float4 p0 = pp4[0], p1 = pp4[1];
  float bb[8] = {bc0.x, bc0.y, bc0.z, bc0.w, bc1.x, bc1.y, bc1.z, bc1.w};
  float gg[8] = {g0.x, g0.y, g0.z, g0.w, g1.x, g1.y, g1.z, g1.w};
  float pb[8] = {p0.x, p0.y, p0.z, p0.w, p1.x, p1.y, p1.z, p1.w};

  // ---- phase 1: aggregate + LN for this wave's 16 nodes ----
  for (int s = 0; s < 16; ++s) {
    int rowL = wave * 16 + s;
    int v = blockIdx.x * 64 + rowL;
    int lidx = rowL * HID + ((lr * 8) ^ ((rowL & 7) << 3));  // swizzled, 16B units
    if (v >= N) {
      if (sub == 0) *(uint4*)&As[lidx] = make_uint4(0, 0, 0, 0);
      continue;
    }
    float a[8] = {0.f, 0.f, 0.f, 0.f, 0.f, 0.f, 0.f, 0.f};
    if (sub == 0) addu4(GR[(size_t)v * 16 + lr], a);  // self loop
    int lo = start[v], hi = lo + deg[v];
    int j = lo;
    for (; j + 8 <= hi; j += 8) {
      int c0 = col[j + sub];
      int c1 = col[j + 4 + sub];
      uint4 u0 = GR[(size_t)c0 * 16 + lr];
      uint4 u1 = GR[(size_t)c1 * 16 + lr];
      addu4(u0, a);
      addu4(u1, a);
    }
    for (; j < hi; j += 4)
      if (j + sub < hi) addu4(GR[(size_t)col[j + sub] * 16 + lr], a);

    #pragma unroll
    for (int i = 0; i < 8; ++i) {
      a[i] += __shfl_xor(a[i], 16, 64);
      a[i] += __shfl_xor(a[i], 32, 64);
    }

    float d = dinv[v];
    #pragma unroll
    for (int i = 0; i < 8; ++i) a[i] = fmaf(a[i], d, bb[i]);

    float s1 = 0.f, s2 = 0.f;
    #pragma unroll
    for (int i = 0; i < 8; ++i) { s1 += a[i]; s2 = fmaf(a[i], a[i], s2); }
    #pragma unroll
    for (int off = 1; off <= 8; off <<= 1) {
      s1 += __shfl_xor(s1, off, 64);
      s2 += __shfl_xor(s2, off, 64);
    }
    float mu = s1 * (1.f / HID);
    float var = s2 * (1.f / HID) - mu * mu;
    float inv = rsqrtf(fmaxf(var, 0.f) + LN_EPS);

    float yv[8];
    #pragma unroll
    for (int i = 0; i < 8; ++i) yv[i] = fmaxf(fmaf((a[i] - mu) * inv, gg[i], pb[i]), 0.f);

    if (sub == 0) {
      size_t idx = (size_t)v * 16 + lr;
      uint4 q;
      if (mode == 0) {
        q.x = pack2(yv[0], yv[1]); q.y = pack2(yv[2], yv[3]);
        q.z = pack2(yv[4], yv[5]); q.w = pack2(yv[6], yv[7]);
      } else {
        uint4 po = Aw[idx];
        q.x = pack2(bl2f(po.x) + yv[0], bh2f(po.x) + yv[1]);
        q.y = pack2(bl2f(po.y) + yv[2], bh2f(po.y) + yv[3]);
        q.z = pack2(bl2f(po.z) + yv[4], bh2f(po.z) + yv[5]);
        q.w = pack2(bl2f(po.w) + yv[6], bh2f(po.w) + yv[7]);
      }
      Aw[idx] = q;
      *(uint4*)&As[lidx] = q;
    }
  }

  // ---- phase 2: 16x128 GEMM for this wave's rows ----
  int lg = sub;
  const f32x4 z4 = {0.f, 0.f, 0.f, 0.f};
  f32x4 acc[8];
  #pragma unroll
  for (int j = 0; j < 8; ++j) acc[j] = z4;

  #pragma unroll
  for (int kk = 0; kk < 4; ++kk) {
    int k0 = kk * 32 + lg * 8;
    int rowA = wave * 16 + lr;
    s16x8 af = *(const s16x8*)&As[rowA * HID + (k0 ^ ((rowA & 7) << 3))];
    #pragma unroll
    for (int nf = 0; nf < 8; ++nf) {
      s16x8 b = *(const s16x8*)(Wt + (size_t)(nf * 16 + lr) * HID + k0);
      acc[nf] = __builtin_amdgcn_mfma_f32_16x16x32_bf16(af, b, acc[nf], 0, 0, 0);
    }
  }

  short* wsl = As + wave * 16 * HID;
  float dv[4];
  #pragma unroll
  for (int r = 0; r < 4; ++r) {
    int row = blockIdx.x * 64 + wave * 16 + lg * 4 + r;
    dv[r] = (row < N) ? dinv[row] : 1.f;
  }
  #pragma unroll
  for (int r = 0; r < 4; ++r) {
    int ri = lg * 4 + r;
    #pragma unroll
    for (int nf = 0; nf < 8; ++nf)
      wsl[ri * HID + nf * 16 + lr] = f2b(acc[nf][r] * dv[r]);
  }
  // wave-local LDS write->read (compiler orders via lgkmcnt)
  #pragma unroll
  for (int it = 0; it < 4; ++it) {
    int rl = it * 4 + sub;
    int row = blockIdx.x * 64 + wave * 16 + rl;
    s16x8 vv = *(const s16x8*)(wsl + rl * HID + lr * 8);
    if (row < N) *(s16x8*)(G_out + (size_t)row * HID + lr * 8) = vv;
  }
}

// ---------------- final aggregation + LayerNorm + ReLU (no GEMM after) ----------------

__global__ __launch_bounds__(256) void agg_ln_kernel(
    const short* __restrict__ G, const int* __restrict__ start, const int* __restrict__ deg,
    const float* __restrict__ dinv, const float* __restrict__ bias,
    const float* __restrict__ lng, const float* __restrict__ lnb,
    const int* __restrict__ col, short* __restrict__ y, int N) {
  int wave = threadIdx.x >> 6, l = threadIdx.x & 63;
  int v = blockIdx.x * 4 + wave;
  if (v >= N) return;
  int lr = l & 15, sub = l >> 4;

  const uint4* GR = (const uint4*)G;
  float a[8] = {0.f, 0.f, 0.f, 0.f, 0.f, 0.f, 0.f, 0.f};

  if (sub == 0) addu4(GR[(size_t)v * 16 + lr], a);

  int lo = start[v], hi = lo + deg[v];
  int j = lo;
  for (; j + 8 <= hi; j += 8) {
    int c0 = col[j + sub];
    int c1 = col[j + 4 + sub];
    uint4 u0 = GR[(size_t)c0 * 16 + lr];
    uint4 u1 = GR[(size_t)c1 * 16 + lr];
    addu4(u0, a);
    addu4(u1, a);
  }
  for (; j < hi; j += 4)
    if (j + sub < hi) addu4(GR[(size_t)col[j + sub] * 16 + lr], a);

  #pragma unroll
  for (int i = 0; i < 8; ++i) {
    a[i] += __shfl_xor(a[i], 16, 64);
    a[i] += __shfl_xor(a[i], 32, 64);
  }

  float d = dinv[v];
  const float4* bp4 = (const float4*)(bias + 8 * lr);
  float4 bc0 = bp4[0], bc1 = bp4[1];
  float bb[8] = {bc0.x, bc0.y, bc0.z, bc0.w, bc1.x, bc1.y, bc1.z, bc1.w};
  #pragma unroll
  for (int i = 0; i < 8; ++i) a[i] = fmaf(a[i], d, bb[i]);

  float s1 = 0.f, s2 = 0.f;
  #pragma unroll
  for (int i = 0; i < 8; ++i) { s1 += a[i]; s2 = fmaf(a[i], a[i], s2); }
  #pragma unroll
  for (int off = 1; off <= 8; off <<= 1) {
    s1 += __shfl_xor(s1, off, 64);
    s2 += __shfl_xor(s2, off, 64);
  }
  float mu = s1 * (1.f / HID);
  float var = s2 * (1.f / HID) - mu * mu;
  float inv = rsqrtf(fmaxf(var, 0.f) + LN_EPS);

  const float4* gp4 = (const float4*)(lng + 8 * lr);
  const float4* pp4 = (const float4*)(lnb + 8 * lr);
  float4 g0 = gp4[0], g1 = gp4[1], p0 = pp4[0], p1 = pp4[1];
  float gg[8] = {g0.x, g0.y, g0.z, g0.w, g1.x, g1.y, g1.z, g1.w};
  float pb[8] = {p0.x, p0.y, p0.z, p0.w, p1.x, p1.y, p1.z, p1.w};
  float yv[8];
  #pragma unroll
  for (int i = 0; i < 8; ++i) yv[i] = fmaxf(fmaf((a[i] - mu) * inv, gg[i], pb[i]), 0.f);

  if (sub == 0) {
    uint4 o;
    o.x = pack2(yv[0], yv[1]); o.y = pack2(yv[2], yv[3]);
    o.z = pack2(yv[4], yv[5]); o.w = pack2(yv[6], yv[7]);
    ((uint4*)y)[(size_t)v * 16 + lr] = o;
  }
}

// ---------------- pooling + post MLP ----------------

__device__ inline int lower_bound_i(const int* a, int n, int key) {
  int lo = 0, hi = n;
  while (lo < hi) { int m = (lo + hi) >> 1; if (a[m] < key) lo = m + 1; else hi = m; }
  return lo;
}

__global__ __launch_bounds__(128) void pool_post_kernel(
    const short* __restrict__ Yl, const int* __restrict__ batch, int n,
    const float* __restrict__ Wp, const float* __restrict__ bp,
    float* __restrict__ out, int n_out) {
  int g = blockIdx.x, t = threadIdx.x;
  int wave = t >> 6;
  int lr = t & 15, slot = t >> 4;  // 8 row-slots x 16 lanes
  int lo = lower_bound_i(batch, n, g);
  int hi = lower_bound_i(batch, n, g + 1);
  const uint4* YR = (const uint4*)Yl;
  float a[8] = {0.f, 0.f, 0.f, 0.f, 0.f, 0.f, 0.f, 0.f};
  for (int r = lo + slot; r < hi; r += 8) addu4(YR[(size_t)r * 16 + lr], a);
  #pragma unroll
  for (int i = 0; i < 8; ++i) {
    a[i] += __shfl_xor(a[i], 16, 64);
    a[i] += __shfl_xor(a[i], 32, 64);
  }
  __shared__ float ls[2][HID];
  if ((slot & 3) == 0) {
    #pragma unroll
    for (int i = 0; i < 8; ++i) ls[wave][8 * lr + i] = a[i];
  }
  __syncthreads();
  if (t < n_out) {
    float o = bp[t];
    #pragma unroll 8
    for (int k = 0; k < HID; ++k) o = fmaf(ls[0][k] + ls[1][k], Wp[k * n_out + t], o);
    out[g * n_out + t] = o;
  }
}

// ---------------- launch ----------------

extern "C" void kernel_launch(void* const* d_in, const int* in_sizes, int n_in,
                              void* d_out, int out_size, void* d_ws, size_t ws_size,
                              hipStream_t stream) {
  const float* x      = (const float*)d_in[0];
  const int*   ei     = (const int*)d_in[1];
  const int*   batch  = (const int*)d_in[2];
  const float* W_pre  = (const float*)d_in[3];
  const float* b_pre  = (const float*)d_in[4];
  const float* conv_W = (const float*)d_in[5];
  const float* conv_b = (const float*)d_in[6];
  const float* ln_g   = (const float*)d_in[7];
  const float* ln_b   = (const float*)d_in[8];
  const float* W_post = (const float*)d_in[9];
  const float* b_post = (const float*)d_in[10];
  float* out = (float*)d_out;

  const int N = in_sizes[2];          // 50000
  const int E = in_sizes[1] / 2;      // 600000
  const int OUT_DIM = 10;
  const int NG = out_size / OUT_DIM;  // 512

  // workspace carve (all 16B-aligned)
  char* p = (char*)d_ws;
  short* ACC = (short*)p;            p += (size_t)N * HID * 2;   // bf16 running sum
  short* G0  = (short*)p;            p += (size_t)N * HID * 2;   // bf16 ping
  short* G1  = (short*)p;            p += (size_t)N * HID * 2;   // bf16 pong
  short* Wt  = (short*)p;            p += (size_t)4 * HID * HID * 2;
  float* Wc  = (float*)p;            p += (size_t)HID * HID * 4; // combined pre-weight fp32
  float* bpr = (float*)p;            p += (size_t)HID * 4;
  float* dinv = (float*)p;           p += (size_t)N * 4;
  int* deg   = (int*)p;              p += (size_t)(N + 1) * 4;   // [N] = global counter
  int* startv = (int*)p;             p += (size_t)N * 4;
  int* cur   = (int*)p;              p += (size_t)N * 4;
  int* col   = (int*)p;              p += (size_t)E * 4;
  int* cnt   = deg + N;

  const int* srcp = ei;
  const int* dstp = ei + E;

  int nb256 = (N + 255) / 256;
  int eb256 = (E + 255) / 256;
  int gemm_grid = (N + 127) / 128;
  int fused_grid = (N + 63) / 64;
  int agg_grid = (N + 3) / 4;

  // weight prep
  prep_comb_kernel<<<HID + 1, HID, 0, stream>>>(W_pre, b_pre, conv_W, Wc, bpr);
  prep_w_kernel<<<4 * HID, 64, 0, stream>>>(Wc, conv_W, Wt);

  // CSR + dinv (scan-free)
  zero_ints_kernel<<<nb256, 256, 0, stream>>>(deg, N + 1);
  deg_count_kernel<<<eb256, 256, 0, stream>>>(dstp, E, deg);
  alloc_kernel<<<nb256, 256, 0, stream>>>(deg, startv, cur, dinv, cnt, N);
  fill_csr_kernel<<<eb256, 256, 0, stream>>>(srcp, dstp, E, cur, col);

  // cell 0 GEMM (pre-MLP folded): G0 = dinv*(x@Wc + b')
  gemm_mfma_kernel<true><<<gemm_grid, 256, 0, stream>>>(x, Wt + 0 * 16384, bpr, dinv, G0, N);

  // fused cells: agg_i + LN + gemm_{i+1}
  agg_ln_gemm_kernel<<<fused_grid, 256, 0, stream>>>(G0, startv, deg, dinv, conv_b + 0 * HID,
                                                     ln_g + 0 * HID, ln_b + 0 * HID, col,
                                                     ACC, Wt + 1 * 16384, G1, N, 0);
  agg_ln_gemm_kernel<<<fused_grid, 256, 0, stream>>>(G1, startv, deg, dinv, conv_b + 1 * HID,
                                                     ln_g + 1 * HID, ln_b + 1 * HID, col,
                                                     ACC, Wt + 2 * 16384, G0, N, 1);
  agg_ln_gemm_kernel<<<fused_grid, 256, 0, stream>>>(G0, startv, deg, dinv, conv_b + 2 * HID,
                                                     ln_g + 2 * HID, ln_b + 2 * HID, col,
                                                     ACC, Wt + 3 * 16384, G1, N, 1);
  // final agg (cell 3) -> y3 in G0
  agg_ln_kernel<<<agg_grid, 256, 0, stream>>>(G1, startv, deg, dinv, conv_b + 3 * HID,
                                              ln_g + 3 * HID, ln_b + 3 * HID, col, G0, N);

  // pooling + post MLP
  pool_post_kernel<<<NG, 128, 0, stream>>>(G0, batch, N, W_post, b_post, out, OUT_DIM);
}

// Round 6
// 298.273 us; speedup vs baseline: 1.1536x; 1.1536x over previous
//
#include <hip/hip_runtime.h>

#define HID 128
#define LN_EPS 1e-5f

using f32x4 = __attribute__((ext_vector_type(4))) float;
using s16x8 = __attribute__((ext_vector_type(8))) short;

__device__ inline float bl2f(unsigned u) { u <<= 16; return __builtin_bit_cast(float, u); }
__device__ inline float bh2f(unsigned u) { u &= 0xffff0000u; return __builtin_bit_cast(float, u); }
__device__ inline float sb2f(short s) {
  unsigned u = ((unsigned)(unsigned short)s) << 16;
  return __builtin_bit_cast(float, u);
}
__device__ inline unsigned f2b_bits(float f) {
  unsigned u = __builtin_bit_cast(unsigned, f);
  return (u + 0x7fffu + ((u >> 16) & 1u)) >> 16;  // RNE
}
__device__ inline short f2b(float f) { return (short)f2b_bits(f); }
__device__ inline unsigned pack2(float a, float b) { return f2b_bits(a) | (f2b_bits(b) << 16); }

__device__ inline void addu4(const uint4 u, float a[8]) {
  a[0] += bl2f(u.x); a[1] += bh2f(u.x);
  a[2] += bl2f(u.y); a[3] += bh2f(u.y);
  a[4] += bl2f(u.z); a[5] += bh2f(u.z);
  a[6] += bl2f(u.w); a[7] += bh2f(u.w);
}

// ---------------- weight prep: Wt[w][n][k] = bf16(src_w[k][n]); w=0 -> W_pre, w>=1 -> conv_W[w-1] ----------------

__global__ __launch_bounds__(64) void prep_w_kernel(const float* __restrict__ W_pre,
                                                    const float* __restrict__ conv_W,
                                                    short* __restrict__ Wt) {
  int b = blockIdx.x;            // 0..639
  int w = b >> 7, n = b & 127;
  const float* W = (w == 0) ? W_pre : conv_W + (size_t)(w - 1) * HID * HID;
  int t = threadIdx.x;           // k = 2t, 2t+1
  float f0 = W[(2 * t) * HID + n];
  float f1 = W[(2 * t + 1) * HID + n];
  ((unsigned*)Wt)[(size_t)(w * HID + n) * 64 + t] = pack2(f0, f1);
}

// ---------------- CSR build (scan-free) ----------------

__global__ void zero_ints_kernel(int* __restrict__ p, int n) {
  int i = blockIdx.x * blockDim.x + threadIdx.x;
  if (i < n) p[i] = 0;
}

__global__ void deg_count_kernel(const int* __restrict__ dst, int E, int* __restrict__ deg) {
  int e = blockIdx.x * blockDim.x + threadIdx.x;
  if (e < E) atomicAdd(&deg[dst[e]], 1);
}

__global__ __launch_bounds__(256) void alloc_kernel(const int* __restrict__ deg,
                                                    int* __restrict__ start,
                                                    int* __restrict__ cur,
                                                    float* __restrict__ dinv,
                                                    int* __restrict__ cnt, int n) {
  __shared__ int wt[4];
  __shared__ int bbase;
  int t = threadIdx.x, lane = t & 63, wid = t >> 6;
  int i = blockIdx.x * 256 + t;
  int d = (i < n) ? deg[i] : 0;
  int x = d;
  #pragma unroll
  for (int off = 1; off < 64; off <<= 1) {
    int u = __shfl_up(x, off, 64);
    if (lane >= off) x += u;
  }
  if (lane == 63) wt[wid] = x;
  __syncthreads();
  if (t == 0) bbase = atomicAdd(cnt, wt[0] + wt[1] + wt[2] + wt[3]);
  __syncthreads();
  int wbase = bbase;
  for (int w = 0; w < wid; ++w) wbase += wt[w];
  int excl = wbase + x - d;
  if (i < n) {
    start[i] = excl;
    cur[i] = excl;
    dinv[i] = rsqrtf((float)(d + 1));
  }
}

__global__ void fill_csr_kernel(const int* __restrict__ src, const int* __restrict__ dst,
                                int E, int* __restrict__ cur, int* __restrict__ col) {
  int e = blockIdx.x * blockDim.x + threadIdx.x;
  if (e < E) {
    int d = dst[e];
    int p = atomicAdd(&cur[d], 1);
    col[p] = src[e];
  }
}

// ---------------- MFMA GEMM (cell-0 pre): S0 = dinv*(x@W_pre^T + b_pre) ----------------

template<bool AF32>
__global__ __launch_bounds__(256) void gemm_mfma_kernel(
    const void* __restrict__ Xv, const short* __restrict__ Wt,
    const float* __restrict__ bias, const float* __restrict__ dinv,
    short* __restrict__ Y, int M) {
  __shared__ short lds[4 * 32 * HID];  // 32 KB
  int t = threadIdx.x;
  int wave = t >> 6, l = t & 63;
  int lg = l >> 4, lr = l & 15;
  int mb = blockIdx.x * 128 + wave * 32;

  const f32x4 z4 = {0.f, 0.f, 0.f, 0.f};
  f32x4 acc[2][8];
  #pragma unroll
  for (int i = 0; i < 2; ++i)
    #pragma unroll
    for (int j = 0; j < 8; ++j) acc[i][j] = z4;

  const short* Xb = (const short*)Xv;
  const float* Xf = (const float*)Xv;

  #pragma unroll
  for (int kk = 0; kk < 4; ++kk) {
    int k0 = kk * 32 + lg * 8;
    s16x8 a[2];
    #pragma unroll
    for (int mf = 0; mf < 2; ++mf) {
      int row = mb + mf * 16 + lr;
      s16x8 av = {0, 0, 0, 0, 0, 0, 0, 0};
      if (row < M) {
        if constexpr (AF32) {
          const float4* p = (const float4*)(Xf + (size_t)row * HID + k0);
          float4 x0 = p[0], x1 = p[1];
          av[0] = f2b(x0.x); av[1] = f2b(x0.y); av[2] = f2b(x0.z); av[3] = f2b(x0.w);
          av[4] = f2b(x1.x); av[5] = f2b(x1.y); av[6] = f2b(x1.z); av[7] = f2b(x1.w);
        } else {
          av = *(const s16x8*)(Xb + (size_t)row * HID + k0);
        }
      }
      a[mf] = av;
    }
    #pragma unroll
    for (int nf = 0; nf < 8; ++nf) {
      s16x8 b = *(const s16x8*)(Wt + (size_t)(nf * 16 + lr) * HID + k0);
      acc[0][nf] = __builtin_amdgcn_mfma_f32_16x16x32_bf16(a[0], b, acc[0][nf], 0, 0, 0);
      acc[1][nf] = __builtin_amdgcn_mfma_f32_16x16x32_bf16(a[1], b, acc[1][nf], 0, 0, 0);
    }
  }

  float bv[8];
  #pragma unroll
  for (int nf = 0; nf < 8; ++nf) bv[nf] = bias ? bias[nf * 16 + lr] : 0.f;

  short* wsl = lds + wave * 32 * HID;
  #pragma unroll
  for (int mf = 0; mf < 2; ++mf) {
    #pragma unroll
    for (int r = 0; r < 4; ++r) {
      int ri = mf * 16 + lg * 4 + r;
      int row = mb + ri;
      float dv = 1.f;
      if (dinv && row < M) dv = dinv[row];
      #pragma unroll
      for (int nf = 0; nf < 8; ++nf) {
        float v = (acc[mf][nf][r] + bv[nf]) * dv;
        wsl[ri * HID + nf * 16 + lr] = f2b(v);
      }
    }
  }
  __syncthreads();

  #pragma unroll
  for (int it = 0; it < 8; ++it) {
    int ro = it * 4 + lg;
    int row = mb + ro;
    s16x8 v = *(const s16x8*)(wsl + it * 512 + l * 8);
    if (row < M) *(s16x8*)(Y + (size_t)row * HID + lr * 8) = v;
  }
}

// ---------------- FUSED cell: gather(S_in) -> GEMM(W) -> +b -> LN -> ReLU -> S_out ----------------
// Uses A(XW) = (AX)W: gather FIRST on pre-scaled rows, conv GEMM after.
// 512 threads (8 waves), 16 nodes/block, 2 nodes/wave in phase 1 -> 25000 waves total.
// Phase 2: wave w computes cols w*16..w*16+15 of the 16x128 GEMM via 4 MFMAs,
// LN stats per row via lr-shuffle + cross-wave LDS reduce.
// mode 0: S_out = dinv*y;  mode 1: S_out = S_in + dinv*y;  mode 2: S_out = y (final).

__global__ __launch_bounds__(512) void cell_kernel(
    const short* __restrict__ Sin, const int* __restrict__ start,
    const int* __restrict__ deg, const float* __restrict__ dinv,
    const int* __restrict__ col, const short* __restrict__ Wt,
    const float* __restrict__ bconv, const float* __restrict__ lng,
    const float* __restrict__ lnb, short* __restrict__ Sout,
    int N, int mode) {
  __shared__ short Zs[16 * HID];       // 4 KB
  __shared__ float red[16][8][2];      // 1 KB
  int t = threadIdx.x;
  int wave = t >> 6, l = t & 63, lr = l & 15, sub = l >> 4;
  int lg = sub;
  const uint4* GR = (const uint4*)Sin;

  // ---- phase 1: gather z = dinv[v] * (sum S_in[neigh] + S_in[v]) for 2 nodes/wave ----
  #pragma unroll
  for (int s2 = 0; s2 < 2; ++s2) {
    int rowL = wave * 2 + s2;
    int v = blockIdx.x * 16 + rowL;
    int zofs = rowL * HID + ((lr * 8) ^ ((rowL & 7) << 3));  // swizzled short index
    if (v >= N) {
      if (sub == 0) *(uint4*)&Zs[zofs] = make_uint4(0u, 0u, 0u, 0u);
      continue;
    }
    float a[8] = {0.f, 0.f, 0.f, 0.f, 0.f, 0.f, 0.f, 0.f};
    if (sub == 0) addu4(GR[(size_t)v * 16 + lr], a);  // self loop
    int lo = start[v], hi = lo + deg[v];
    int j = lo;
    for (; j + 8 <= hi; j += 8) {
      int c0 = col[j + sub];
      int c1 = col[j + 4 + sub];
      uint4 u0 = GR[(size_t)c0 * 16 + lr];
      uint4 u1 = GR[(size_t)c1 * 16 + lr];
      addu4(u0, a);
      addu4(u1, a);
    }
    for (; j < hi; j += 4)
      if (j + sub < hi) addu4(GR[(size_t)col[j + sub] * 16 + lr], a);

    #pragma unroll
    for (int i = 0; i < 8; ++i) {
      a[i] += __shfl_xor(a[i], 16, 64);
      a[i] += __shfl_xor(a[i], 32, 64);
    }
    float d = dinv[v];
    if (sub == 0) {
      uint4 q;
      q.x = pack2(a[0] * d, a[1] * d); q.y = pack2(a[2] * d, a[3] * d);
      q.z = pack2(a[4] * d, a[5] * d); q.w = pack2(a[6] * d, a[7] * d);
      *(uint4*)&Zs[zofs] = q;
    }
  }
  __syncthreads();

  // ---- phase 2: 16x128 GEMM, this wave's 16 cols; h = z@W + b; LN stats ----
  f32x4 acc = {0.f, 0.f, 0.f, 0.f};
  #pragma unroll
  for (int kk = 0; kk < 4; ++kk) {
    int k0 = kk * 32 + lg * 8;
    s16x8 af = *(const s16x8*)&Zs[lr * HID + (k0 ^ ((lr & 7) << 3))];
    s16x8 bf = *(const s16x8*)(Wt + (size_t)(wave * 16 + lr) * HID + k0);
    acc = __builtin_amdgcn_mfma_f32_16x16x32_bf16(af, bf, acc, 0, 0, 0);
  }
  int c = wave * 16 + lr;  // output column
  float bc = bconv[c];
  float h[4], s1[4], s2v[4];
  #pragma unroll
  for (int r = 0; r < 4; ++r) {
    h[r] = acc[r] + bc;           // row lg*4+r, col c
    s1[r] = h[r];
    s2v[r] = h[r] * h[r];
  }
  #pragma unroll
  for (int off = 1; off <= 8; off <<= 1) {
    #pragma unroll
    for (int r = 0; r < 4; ++r) {
      s1[r] += __shfl_xor(s1[r], off, 64);
      s2v[r] += __shfl_xor(s2v[r], off, 64);
    }
  }
  if (lr == 0) {
    #pragma unroll
    for (int r = 0; r < 4; ++r) {
      red[lg * 4 + r][wave][0] = s1[r];
      red[lg * 4 + r][wave][1] = s2v[r];
    }
  }
  __syncthreads();
  float gl = lng[c], bl = lnb[c];
  #pragma unroll
  for (int r = 0; r < 4; ++r) {
    int row = lg * 4 + r;
    const float4* rp = (const float4*)&red[row][0][0];
    float t1 = 0.f, t2 = 0.f;
    #pragma unroll
    for (int q4 = 0; q4 < 4; ++q4) {
      float4 vv = rp[q4];
      t1 += vv.x + vv.z;
      t2 += vv.y + vv.w;
    }
    float mu = t1 * (1.f / HID);
    float var = t2 * (1.f / HID) - mu * mu;
    float inv = rsqrtf(fmaxf(var, 0.f) + LN_EPS);
    float yv = fmaxf(fmaf((h[r] - mu) * inv, gl, bl), 0.f);
    Zs[row * HID + (c ^ ((row & 7) << 3))] = f2b(yv);
  }
  __syncthreads();

  // ---- phase 3: write S_out (coalesced 16B) ----
  if (t < 256) {
    int row = t >> 4, q = t & 15;
    int v = blockIdx.x * 16 + row;
    if (v < N) {
      s16x8 y8 = *(const s16x8*)&Zs[row * HID + ((q * 8) ^ ((row & 7) << 3))];
      float yv[8];
      #pragma unroll
      for (int i = 0; i < 8; ++i) yv[i] = sb2f(y8[i]);
      uint4 o;
      if (mode == 2) {
        o.x = pack2(yv[0], yv[1]); o.y = pack2(yv[2], yv[3]);
        o.z = pack2(yv[4], yv[5]); o.w = pack2(yv[6], yv[7]);
      } else if (mode == 0) {
        float d = dinv[v];
        o.x = pack2(yv[0] * d, yv[1] * d); o.y = pack2(yv[2] * d, yv[3] * d);
        o.z = pack2(yv[4] * d, yv[5] * d); o.w = pack2(yv[6] * d, yv[7] * d);
      } else {
        float d = dinv[v];
        uint4 ui = GR[(size_t)v * 16 + q];
        o.x = pack2(bl2f(ui.x) + yv[0] * d, bh2f(ui.x) + yv[1] * d);
        o.y = pack2(bl2f(ui.y) + yv[2] * d, bh2f(ui.y) + yv[3] * d);
        o.z = pack2(bl2f(ui.z) + yv[4] * d, bh2f(ui.z) + yv[5] * d);
        o.w = pack2(bl2f(ui.w) + yv[6] * d, bh2f(ui.w) + yv[7] * d);
      }
      ((uint4*)Sout)[(size_t)v * 16 + q] = o;
    }
  }
}

// ---------------- pooling + post MLP ----------------

__device__ inline int lower_bound_i(const int* a, int n, int key) {
  int lo = 0, hi = n;
  while (lo < hi) { int m = (lo + hi) >> 1; if (a[m] < key) lo = m + 1; else hi = m; }
  return lo;
}

__global__ __launch_bounds__(128) void pool_post_kernel(
    const short* __restrict__ Yl, const int* __restrict__ batch, int n,
    const float* __restrict__ Wp, const float* __restrict__ bp,
    float* __restrict__ out, int n_out) {
  int g = blockIdx.x, t = threadIdx.x;
  int wave = t >> 6;
  int lr = t & 15, slot = t >> 4;
  int lo = lower_bound_i(batch, n, g);
  int hi = lower_bound_i(batch, n, g + 1);
  const uint4* YR = (const uint4*)Yl;
  float a[8] = {0.f, 0.f, 0.f, 0.f, 0.f, 0.f, 0.f, 0.f};
  for (int r = lo + slot; r < hi; r += 8) addu4(YR[(size_t)r * 16 + lr], a);
  #pragma unroll
  for (int i = 0; i < 8; ++i) {
    a[i] += __shfl_xor(a[i], 16, 64);
    a[i] += __shfl_xor(a[i], 32, 64);
  }
  __shared__ float ls[2][HID];
  if ((slot & 3) == 0) {
    #pragma unroll
    for (int i = 0; i < 8; ++i) ls[wave][8 * lr + i] = a[i];
  }
  __syncthreads();
  if (t < n_out) {
    float o = bp[t];
    #pragma unroll 8
    for (int k = 0; k < HID; ++k) o = fmaf(ls[0][k] + ls[1][k], Wp[k * n_out + t], o);
    out[g * n_out + t] = o;
  }
}

// ---------------- launch ----------------

extern "C" void kernel_launch(void* const* d_in, const int* in_sizes, int n_in,
                              void* d_out, int out_size, void* d_ws, size_t ws_size,
                              hipStream_t stream) {
  const float* x      = (const float*)d_in[0];
  const int*   ei     = (const int*)d_in[1];
  const int*   batch  = (const int*)d_in[2];
  const float* W_pre  = (const float*)d_in[3];
  const float* b_pre  = (const float*)d_in[4];
  const float* conv_W = (const float*)d_in[5];
  const float* conv_b = (const float*)d_in[6];
  const float* ln_g   = (const float*)d_in[7];
  const float* ln_b   = (const float*)d_in[8];
  const float* W_post = (const float*)d_in[9];
  const float* b_post = (const float*)d_in[10];
  float* out = (float*)d_out;

  const int N = in_sizes[2];          // 50000
  const int E = in_sizes[1] / 2;      // 600000
  const int OUT_DIM = 10;
  const int NG = out_size / OUT_DIM;  // 512

  // workspace carve (all 16B-aligned)
  char* p = (char*)d_ws;
  short* SA  = (short*)p;            p += (size_t)N * HID * 2;   // bf16
  short* SB  = (short*)p;            p += (size_t)N * HID * 2;   // bf16
  short* Wt  = (short*)p;            p += (size_t)5 * HID * HID * 2;
  float* dinv = (float*)p;           p += (size_t)N * 4;
  int* deg   = (int*)p;              p += (size_t)(N + 1) * 4;   // [N] = global counter
  int* startv = (int*)p;             p += (size_t)N * 4;
  int* cur   = (int*)p;              p += (size_t)N * 4;
  int* col   = (int*)p;              p += (size_t)E * 4;
  int* cnt   = deg + N;

  const int* srcp = ei;
  const int* dstp = ei + E;

  int nb256 = (N + 255) / 256;
  int eb256 = (E + 255) / 256;
  int gemm_grid = (N + 127) / 128;
  int cell_grid = (N + 15) / 16;

  // weight prep (W_pre + 4 conv weights)
  prep_w_kernel<<<5 * HID, 64, 0, stream>>>(W_pre, conv_W, Wt);

  // CSR + dinv (scan-free)
  zero_ints_kernel<<<nb256, 256, 0, stream>>>(deg, N + 1);
  deg_count_kernel<<<eb256, 256, 0, stream>>>(dstp, E, deg);
  alloc_kernel<<<nb256, 256, 0, stream>>>(deg, startv, cur, dinv, cnt, N);
  fill_csr_kernel<<<eb256, 256, 0, stream>>>(srcp, dstp, E, cur, col);

  // S0 = dinv * (x @ W_pre + b_pre)  -> SA
  gemm_mfma_kernel<true><<<gemm_grid, 256, 0, stream>>>(x, Wt + 0 * 16384, b_pre, dinv, SA, N);

  // cell 0: SA -> SB = dinv*y0
  cell_kernel<<<cell_grid, 512, 0, stream>>>(SA, startv, deg, dinv, col, Wt + 1 * 16384,
                                             conv_b + 0 * HID, ln_g + 0 * HID, ln_b + 0 * HID,
                                             SB, N, 0);
  // cell 1: SB -> SA = SB + dinv*y1
  cell_kernel<<<cell_grid, 512, 0, stream>>>(SB, startv, deg, dinv, col, Wt + 2 * 16384,
                                             conv_b + 1 * HID, ln_g + 1 * HID, ln_b + 1 * HID,
                                             SA, N, 1);
  // cell 2: SA -> SB = SA + dinv*y2
  cell_kernel<<<cell_grid, 512, 0, stream>>>(SA, startv, deg, dinv, col, Wt + 3 * 16384,
                                             conv_b + 2 * HID, ln_g + 2 * HID, ln_b + 2 * HID,
                                             SB, N, 1);
  // cell 3: SB -> SA = y3 (unscaled, pooling source)
  cell_kernel<<<cell_grid, 512, 0, stream>>>(SB, startv, deg, dinv, col, Wt + 4 * 16384,
                                             conv_b + 3 * HID, ln_g + 3 * HID, ln_b + 3 * HID,
                                             SA, N, 2);

  // pooling + post MLP
  pool_post_kernel<<<NG, 128, 0, stream>>>(SA, batch, N, W_post, b_post, out, OUT_DIM);
}